// Round 4
// baseline (959.475 us; speedup 1.0000x reference)
//
#include <hip/hip_runtime.h>
#include <math.h>
#include <stdint.h>

#define HC 4
#define HIDDEN 4096
#define DIM (HC * HIDDEN)          // 16384 floats per row
#define MIXN ((2 + HC) * HC)       // 24
#define RPB 8                      // rows per block
#define THREADS 256
#define NWAVE 4
#define MPW (MIXN / NWAVE)         // 6 gate columns per wave
#define CHUNK 512                  // floats per row per K-chunk
#define NCHUNK (DIM / CHUNK)       // 32
#define NROWS (2 * 4096)           // B*S = 8192
#define HC_EPS 1e-5f
#define NORM_EPS 1e-6f

#define PRE_OFF 0
#define POST_OFF (NROWS * HC)            // 32768
#define COMB_OFF (2 * NROWS * HC)        // 65536

typedef float f32x4 __attribute__((ext_vector_type(4)));

__device__ __forceinline__ void g2lds16(const float* g, float* l) {
    // 16B per lane; LDS dest = wave-uniform base + lane*16 (pass uniform l)
    __builtin_amdgcn_global_load_lds(
        (const __attribute__((address_space(1))) uint32_t*)g,
        (__attribute__((address_space(3))) uint32_t*)l, 16, 0, 0);
}

__global__ __launch_bounds__(THREADS, 4) void hyperconn_kernel(
    const float* __restrict__ hs,    // [NROWS][DIM]
    const float* __restrict__ fn,    // [MIXN][DIM]
    const float* __restrict__ base,  // [MIXN]
    const float* __restrict__ scale, // [3]
    float* __restrict__ out)
{
    const int tid  = threadIdx.x;
    const int wave = tid >> 6;
    const int lane = tid & 63;
    const int row0 = blockIdx.x * RPB;
    const int mg   = wave * MPW;          // this wave's first gate column

    __shared__ __align__(16) float lds[2][RPB][CHUNK];   // 32 KB double-buffered hs tile
    __shared__ float s_fin[RPB * 25];

    float acc[RPB][MPW];
    #pragma unroll
    for (int r = 0; r < RPB; ++r)
        #pragma unroll
        for (int j = 0; j < MPW; ++j) acc[r][j] = 0.0f;
    float ssq0 = 0.0f, ssq1 = 0.0f;       // wave w owns ssq of rows 2w, 2w+1

    const f32x4* __restrict__ fn4 = reinterpret_cast<const f32x4*>(fn);

    // stage chunk t into lds[buf]: wave w stages rows 2w and 2w+1, two 1KB halves each
    auto stage = [&](int t, int buf) {
        #pragma unroll
        for (int rr = 0; rr < 2; ++rr) {
            const int r = 2 * wave + rr;
            const float* gbase = hs + (size_t)(row0 + r) * DIM + t * CHUNK;
            #pragma unroll
            for (int half = 0; half < 2; ++half) {
                g2lds16(gbase + half * 256 + lane * 4, &lds[buf][r][half * 256]);
            }
        }
    };

    stage(0, 0);

    #pragma unroll 1
    for (int t = 0; t < NCHUNK; ++t) {
        __syncthreads();                       // drains vmcnt -> lds[t&1] ready
        if (t + 1 < NCHUNK) stage(t + 1, (t + 1) & 1);
        const int buf = t & 1;

        #pragma unroll
        for (int p = 0; p < 2; ++p) {
            const int idx = p * 64 + lane;     // float4 index within chunk (0..127)

            f32x4 x[RPB];
            #pragma unroll
            for (int r = 0; r < RPB; ++r)
                x[r] = *reinterpret_cast<const f32x4*>(&lds[buf][r][idx * 4]);

            f32x4 f[MPW];
            #pragma unroll
            for (int j = 0; j < MPW; ++j)
                f[j] = fn4[(size_t)(mg + j) * (DIM / 4) + t * (CHUNK / 4) + idx];

            #pragma unroll
            for (int r = 0; r < RPB; ++r)
                #pragma unroll
                for (int j = 0; j < MPW; ++j) {
                    acc[r][j] = fmaf(x[r].x, f[j].x, acc[r][j]);
                    acc[r][j] = fmaf(x[r].y, f[j].y, acc[r][j]);
                    acc[r][j] = fmaf(x[r].z, f[j].z, acc[r][j]);
                    acc[r][j] = fmaf(x[r].w, f[j].w, acc[r][j]);
                }

            const f32x4 a = x[2 * wave], b = x[2 * wave + 1];
            ssq0 = fmaf(a.x, a.x, ssq0); ssq0 = fmaf(a.y, a.y, ssq0);
            ssq0 = fmaf(a.z, a.z, ssq0); ssq0 = fmaf(a.w, a.w, ssq0);
            ssq1 = fmaf(b.x, b.x, ssq1); ssq1 = fmaf(b.y, b.y, ssq1);
            ssq1 = fmaf(b.z, b.z, ssq1); ssq1 = fmaf(b.w, b.w, ssq1);
        }
    }

    // 64-lane butterfly reduce: 48 dot partials + 2 ssq per wave
    #pragma unroll
    for (int r = 0; r < RPB; ++r)
        #pragma unroll
        for (int j = 0; j < MPW; ++j) {
            float v = acc[r][j];
            #pragma unroll
            for (int off = 32; off >= 1; off >>= 1) v += __shfl_xor(v, off, 64);
            acc[r][j] = v;
        }
    #pragma unroll
    for (int off = 32; off >= 1; off >>= 1) ssq0 += __shfl_xor(ssq0, off, 64);
    #pragma unroll
    for (int off = 32; off >= 1; off >>= 1) ssq1 += __shfl_xor(ssq1, off, 64);

    __syncthreads();   // all waves done with lds tile before reusing s_fin window
    if (lane == 0) {
        #pragma unroll
        for (int r = 0; r < RPB; ++r)
            #pragma unroll
            for (int j = 0; j < MPW; ++j) s_fin[r * 25 + mg + j] = acc[r][j];
        s_fin[(2 * wave) * 25 + 24]     = ssq0;
        s_fin[(2 * wave + 1) * 25 + 24] = ssq1;
    }
    __syncthreads();

    // epilogue: one thread per row
    if (tid < RPB) {
        const int row = row0 + tid;
        const float* v = &s_fin[tid * 25];
        const float rs = 1.0f / sqrtf(v[24] * (1.0f / (float)DIM) + NORM_EPS);
        const float s0 = scale[0], s1 = scale[1], s2 = scale[2];

        #pragma unroll
        for (int i = 0; i < HC; ++i) {
            const float z = v[i] * rs * s0 + base[i];
            out[PRE_OFF + row * HC + i] = 1.0f / (1.0f + expf(-z)) + HC_EPS;
        }
        #pragma unroll
        for (int i = 0; i < HC; ++i) {
            const float z = v[HC + i] * rs * s1 + base[HC + i];
            out[POST_OFF + row * HC + i] = 2.0f / (1.0f + expf(-z));
        }

        float c[HC][HC];
        #pragma unroll
        for (int i = 0; i < HC; ++i) {
            float l[HC];
            #pragma unroll
            for (int j = 0; j < HC; ++j)
                l[j] = v[2 * HC + i * HC + j] * rs * s2 + base[2 * HC + i * HC + j];
            const float mx = fmaxf(fmaxf(l[0], l[1]), fmaxf(l[2], l[3]));
            float e[HC];
            float sum = 0.0f;
            #pragma unroll
            for (int j = 0; j < HC; ++j) { e[j] = expf(l[j] - mx); sum += e[j]; }
            const float inv = 1.0f / sum;
            #pragma unroll
            for (int j = 0; j < HC; ++j) c[i][j] = e[j] * inv + HC_EPS;
        }
        #pragma unroll
        for (int j = 0; j < HC; ++j) {
            const float cs = c[0][j] + c[1][j] + c[2][j] + c[3][j] + HC_EPS;
            const float inv = 1.0f / cs;
            c[0][j] *= inv; c[1][j] *= inv; c[2][j] *= inv; c[3][j] *= inv;
        }
        #pragma unroll
        for (int it = 0; it < 4; ++it) {
            #pragma unroll
            for (int i = 0; i < HC; ++i) {
                const float rsum = c[i][0] + c[i][1] + c[i][2] + c[i][3] + HC_EPS;
                const float inv = 1.0f / rsum;
                c[i][0] *= inv; c[i][1] *= inv; c[i][2] *= inv; c[i][3] *= inv;
            }
            #pragma unroll
            for (int j = 0; j < HC; ++j) {
                const float cs = c[0][j] + c[1][j] + c[2][j] + c[3][j] + HC_EPS;
                const float inv = 1.0f / cs;
                c[0][j] *= inv; c[1][j] *= inv; c[2][j] *= inv; c[3][j] *= inv;
            }
        }
        #pragma unroll
        for (int i = 0; i < HC; ++i)
            #pragma unroll
            for (int j = 0; j < HC; ++j)
                out[COMB_OFF + row * (HC * HC) + i * HC + j] = c[i][j];
    }
}

extern "C" void kernel_launch(void* const* d_in, const int* in_sizes, int n_in,
                              void* d_out, int out_size, void* d_ws, size_t ws_size,
                              hipStream_t stream) {
    const float* hs    = (const float*)d_in[0];
    const float* fn    = (const float*)d_in[1];
    const float* base  = (const float*)d_in[2];
    const float* scale = (const float*)d_in[3];
    float* out = (float*)d_out;

    const int grid = NROWS / RPB;  // 1024 blocks -> 4 blocks/CU, fully co-resident
    hyperconn_kernel<<<grid, THREADS, 0, stream>>>(hs, fn, base, scale, out);
}

// Round 5
// 319.905 us; speedup vs baseline: 2.9992x; 2.9992x over previous
//
#include <hip/hip_runtime.h>
#include <math.h>
#include <stdint.h>

#define HC 4
#define HIDDEN 4096
#define DIM (HC * HIDDEN)          // 16384 floats per row
#define MIXN ((2 + HC) * HC)       // 24
#define RPB 8                      // rows per block
#define THREADS 256
#define NWAVE 4
#define MPW (MIXN / NWAVE)         // 6 gate columns per wave
#define CHUNK 512                  // floats per row per K-chunk
#define NCHUNK (DIM / CHUNK)       // 32
#define NROWS (2 * 4096)           // B*S = 8192
#define HC_EPS 1e-5f
#define NORM_EPS 1e-6f

#define PRE_OFF 0
#define POST_OFF (NROWS * HC)            // 32768
#define COMB_OFF (2 * NROWS * HC)        // 65536

typedef float f32x4 __attribute__((ext_vector_type(4)));

__device__ __forceinline__ void g2lds16(const float* g, float* l) {
    // 16B per lane; LDS dest = wave-uniform base + lane*16 (pass uniform l)
    __builtin_amdgcn_global_load_lds(
        (const __attribute__((address_space(1))) uint32_t*)g,
        (__attribute__((address_space(3))) uint32_t*)l, 16, 0, 0);
}

__global__ __launch_bounds__(THREADS, 4) void hyperconn_kernel(
    const float* __restrict__ hs,    // [NROWS][DIM]
    const float* __restrict__ fn,    // [MIXN][DIM]
    const float* __restrict__ base,  // [MIXN]
    const float* __restrict__ scale, // [3]
    float* __restrict__ out)
{
    const int tid  = threadIdx.x;
    const int wave = tid >> 6;
    const int lane = tid & 63;
    const int row0 = blockIdx.x * RPB;
    const int mg   = wave * MPW;          // this wave's first gate column

    __shared__ __align__(16) float lds[2][RPB][CHUNK];   // 32 KB double-buffered hs tile
    __shared__ float s_fin[RPB * 25];

    float acc[RPB][MPW];
    #pragma unroll
    for (int r = 0; r < RPB; ++r)
        #pragma unroll
        for (int j = 0; j < MPW; ++j) acc[r][j] = 0.0f;
    float ssq0 = 0.0f, ssq1 = 0.0f;       // wave w owns ssq of rows 2w, 2w+1

    const f32x4* __restrict__ fn4 = reinterpret_cast<const f32x4*>(fn);

    // stage chunk t into lds[buf]: wave w stages rows 2w and 2w+1, two 1KB halves each
    auto stage = [&](int t, int buf) {
        #pragma unroll
        for (int rr = 0; rr < 2; ++rr) {
            const int r = 2 * wave + rr;
            const float* gbase = hs + (size_t)(row0 + r) * DIM + t * CHUNK;
            #pragma unroll
            for (int half = 0; half < 2; ++half) {
                g2lds16(gbase + half * 256 + lane * 4, &lds[buf][r][half * 256]);
            }
        }
    };

    stage(0, 0);

    // wave-private LDS base for its two ssq rows (runtime LDS address is fine;
    // runtime REGISTER-array index is what forced scratch in the last version)
    const float* ssq_row0;
    const float* ssq_row1;

    #pragma unroll 1
    for (int t = 0; t < NCHUNK; ++t) {
        __syncthreads();                       // drains vmcnt -> lds[t&1] ready
        if (t + 1 < NCHUNK) stage(t + 1, (t + 1) & 1);
        const int buf = t & 1;
        ssq_row0 = &lds[buf][2 * wave][0];
        ssq_row1 = &lds[buf][2 * wave + 1][0];

        #pragma unroll
        for (int p = 0; p < 2; ++p) {
            const int idx = p * 64 + lane;     // float4 index within chunk (0..127)

            f32x4 x[RPB];
            #pragma unroll
            for (int r = 0; r < RPB; ++r)
                x[r] = *reinterpret_cast<const f32x4*>(&lds[buf][r][idx * 4]);

            f32x4 f[MPW];
            #pragma unroll
            for (int j = 0; j < MPW; ++j)
                f[j] = fn4[(size_t)(mg + j) * (DIM / 4) + t * (CHUNK / 4) + idx];

            #pragma unroll
            for (int r = 0; r < RPB; ++r)
                #pragma unroll
                for (int j = 0; j < MPW; ++j) {
                    acc[r][j] = fmaf(x[r].x, f[j].x, acc[r][j]);
                    acc[r][j] = fmaf(x[r].y, f[j].y, acc[r][j]);
                    acc[r][j] = fmaf(x[r].z, f[j].z, acc[r][j]);
                    acc[r][j] = fmaf(x[r].w, f[j].w, acc[r][j]);
                }

            // ssq for this wave's two rows: re-read from LDS (no runtime reg index)
            const f32x4 a = *reinterpret_cast<const f32x4*>(&ssq_row0[idx * 4]);
            const f32x4 b = *reinterpret_cast<const f32x4*>(&ssq_row1[idx * 4]);
            ssq0 = fmaf(a.x, a.x, ssq0); ssq0 = fmaf(a.y, a.y, ssq0);
            ssq0 = fmaf(a.z, a.z, ssq0); ssq0 = fmaf(a.w, a.w, ssq0);
            ssq1 = fmaf(b.x, b.x, ssq1); ssq1 = fmaf(b.y, b.y, ssq1);
            ssq1 = fmaf(b.z, b.z, ssq1); ssq1 = fmaf(b.w, b.w, ssq1);
        }
    }

    // 64-lane butterfly reduce: 48 dot partials + 2 ssq per wave
    #pragma unroll
    for (int r = 0; r < RPB; ++r)
        #pragma unroll
        for (int j = 0; j < MPW; ++j) {
            float v = acc[r][j];
            #pragma unroll
            for (int off = 32; off >= 1; off >>= 1) v += __shfl_xor(v, off, 64);
            acc[r][j] = v;
        }
    #pragma unroll
    for (int off = 32; off >= 1; off >>= 1) ssq0 += __shfl_xor(ssq0, off, 64);
    #pragma unroll
    for (int off = 32; off >= 1; off >>= 1) ssq1 += __shfl_xor(ssq1, off, 64);

    __syncthreads();
    if (lane == 0) {
        #pragma unroll
        for (int r = 0; r < RPB; ++r)
            #pragma unroll
            for (int j = 0; j < MPW; ++j) s_fin[r * 25 + mg + j] = acc[r][j];
        s_fin[(2 * wave) * 25 + 24]     = ssq0;
        s_fin[(2 * wave + 1) * 25 + 24] = ssq1;
    }
    __syncthreads();

    // epilogue: one thread per row
    if (tid < RPB) {
        const int row = row0 + tid;
        const float* v = &s_fin[tid * 25];
        const float rs = 1.0f / sqrtf(v[24] * (1.0f / (float)DIM) + NORM_EPS);
        const float s0 = scale[0], s1 = scale[1], s2 = scale[2];

        #pragma unroll
        for (int i = 0; i < HC; ++i) {
            const float z = v[i] * rs * s0 + base[i];
            out[PRE_OFF + row * HC + i] = 1.0f / (1.0f + expf(-z)) + HC_EPS;
        }
        #pragma unroll
        for (int i = 0; i < HC; ++i) {
            const float z = v[HC + i] * rs * s1 + base[HC + i];
            out[POST_OFF + row * HC + i] = 2.0f / (1.0f + expf(-z));
        }

        float c[HC][HC];
        #pragma unroll
        for (int i = 0; i < HC; ++i) {
            float l[HC];
            #pragma unroll
            for (int j = 0; j < HC; ++j)
                l[j] = v[2 * HC + i * HC + j] * rs * s2 + base[2 * HC + i * HC + j];
            const float mx = fmaxf(fmaxf(l[0], l[1]), fmaxf(l[2], l[3]));
            float e[HC];
            float sum = 0.0f;
            #pragma unroll
            for (int j = 0; j < HC; ++j) { e[j] = expf(l[j] - mx); sum += e[j]; }
            const float inv = 1.0f / sum;
            #pragma unroll
            for (int j = 0; j < HC; ++j) c[i][j] = e[j] * inv + HC_EPS;
        }
        #pragma unroll
        for (int j = 0; j < HC; ++j) {
            const float cs = c[0][j] + c[1][j] + c[2][j] + c[3][j] + HC_EPS;
            const float inv = 1.0f / cs;
            c[0][j] *= inv; c[1][j] *= inv; c[2][j] *= inv; c[3][j] *= inv;
        }
        #pragma unroll
        for (int it = 0; it < 4; ++it) {
            #pragma unroll
            for (int i = 0; i < HC; ++i) {
                const float rsum = c[i][0] + c[i][1] + c[i][2] + c[i][3] + HC_EPS;
                const float inv = 1.0f / rsum;
                c[i][0] *= inv; c[i][1] *= inv; c[i][2] *= inv; c[i][3] *= inv;
            }
            #pragma unroll
            for (int j = 0; j < HC; ++j) {
                const float cs = c[0][j] + c[1][j] + c[2][j] + c[3][j] + HC_EPS;
                const float inv = 1.0f / cs;
                c[0][j] *= inv; c[1][j] *= inv; c[2][j] *= inv; c[3][j] *= inv;
            }
        }
        #pragma unroll
        for (int i = 0; i < HC; ++i)
            #pragma unroll
            for (int j = 0; j < HC; ++j)
                out[COMB_OFF + row * (HC * HC) + i * HC + j] = c[i][j];
    }
}

extern "C" void kernel_launch(void* const* d_in, const int* in_sizes, int n_in,
                              void* d_out, int out_size, void* d_ws, size_t ws_size,
                              hipStream_t stream) {
    const float* hs    = (const float*)d_in[0];
    const float* fn    = (const float*)d_in[1];
    const float* base  = (const float*)d_in[2];
    const float* scale = (const float*)d_in[3];
    float* out = (float*)d_out;

    const int grid = NROWS / RPB;  // 1024 blocks -> 4 blocks/CU, fully co-resident
    hyperconn_kernel<<<grid, THREADS, 0, stream>>>(hs, fn, base, scale, out);
}

// Round 6
// 174.357 us; speedup vs baseline: 5.5029x; 1.8348x over previous
//
#include <hip/hip_runtime.h>
#include <math.h>
#include <stdint.h>

#define HC 4
#define HIDDEN 4096
#define DIM (HC * HIDDEN)          // 16384 floats per row
#define MIXN ((2 + HC) * HC)       // 24
#define RPB 8                      // rows per block
#define THREADS 256
#define NWAVE 4
#define MPW (MIXN / NWAVE)         // 6 gate columns per wave
#define CHUNK 512                  // floats per row per K-chunk
#define NCHUNK (DIM / CHUNK)       // 32
#define NROWS (2 * 4096)           // B*S = 8192
#define HC_EPS 1e-5f
#define NORM_EPS 1e-6f

#define PRE_OFF 0
#define POST_OFF (NROWS * HC)            // 32768
#define COMB_OFF (2 * NROWS * HC)        // 65536

typedef float f32x4 __attribute__((ext_vector_type(4)));

__device__ __forceinline__ void g2lds16(const float* g, float* l) {
    // 16B per lane; LDS dest = wave-uniform base + lane*16 (pass uniform l)
    __builtin_amdgcn_global_load_lds(
        (const __attribute__((address_space(1))) uint32_t*)g,
        (__attribute__((address_space(3))) uint32_t*)l, 16, 0, 0);
}

// NOTE: no second __launch_bounds__ arg. Rounds 4/5 showed that ",4" pinned
// the allocator to 64 VGPRs (below the ~100 live values here) and produced
// 0.4-2.3 GB of scratch traffic. Round 3 without it allocated 104, no spill.
__global__ __launch_bounds__(THREADS) void hyperconn_kernel(
    const float* __restrict__ hs,    // [NROWS][DIM]
    const float* __restrict__ fn,    // [MIXN][DIM]
    const float* __restrict__ base,  // [MIXN]
    const float* __restrict__ scale, // [3]
    float* __restrict__ out)
{
    const int tid  = threadIdx.x;
    const int wave = tid >> 6;
    const int lane = tid & 63;
    const int row0 = blockIdx.x * RPB;
    const int mg   = wave * MPW;          // this wave's first gate column

    __shared__ __align__(16) float lds[2][RPB][CHUNK];   // 32 KB double-buffered hs tile
    __shared__ float s_fin[RPB * 25];

    float acc[RPB][MPW];
    #pragma unroll
    for (int r = 0; r < RPB; ++r)
        #pragma unroll
        for (int j = 0; j < MPW; ++j) acc[r][j] = 0.0f;
    float ssq0 = 0.0f, ssq1 = 0.0f;       // wave w owns ssq of rows 2w, 2w+1

    const f32x4* __restrict__ fn4 = reinterpret_cast<const f32x4*>(fn);

    // stage chunk t into lds[buf]: wave w stages rows 2w and 2w+1, two 1KB halves each
    auto stage = [&](int t, int buf) {
        #pragma unroll
        for (int rr = 0; rr < 2; ++rr) {
            const int r = 2 * wave + rr;
            const float* gbase = hs + (size_t)(row0 + r) * DIM + t * CHUNK;
            #pragma unroll
            for (int half = 0; half < 2; ++half) {
                g2lds16(gbase + half * 256 + lane * 4, &lds[buf][r][half * 256]);
            }
        }
    };

    stage(0, 0);

    #pragma unroll 1
    for (int t = 0; t < NCHUNK; ++t) {
        __syncthreads();                       // drains vmcnt -> lds[t&1] ready
        if (t + 1 < NCHUNK) stage(t + 1, (t + 1) & 1);
        const int buf = t & 1;
        const float* xrow0 = &lds[buf][2 * wave][0];       // this wave's ssq rows
        const float* xrow1 = &lds[buf][2 * wave + 1][0];

        #pragma unroll
        for (int p = 0; p < 2; ++p) {
            const int idx = p * 64 + lane;     // float4 index within chunk (0..127)

            // issue the 6 long-latency fn loads (L2) first
            f32x4 f[MPW];
            #pragma unroll
            for (int j = 0; j < MPW; ++j)
                f[j] = fn4[(size_t)(mg + j) * (DIM / 4) + t * (CHUNK / 4) + idx];

            // rows in two groups of 4 to halve x's live range (reg pressure)
            #pragma unroll
            for (int g = 0; g < 2; ++g) {
                f32x4 x[RPB / 2];
                #pragma unroll
                for (int r = 0; r < RPB / 2; ++r)
                    x[r] = *reinterpret_cast<const f32x4*>(
                        &lds[buf][g * (RPB / 2) + r][idx * 4]);

                #pragma unroll
                for (int r = 0; r < RPB / 2; ++r)
                    #pragma unroll
                    for (int j = 0; j < MPW; ++j) {
                        float& a = acc[g * (RPB / 2) + r][j];
                        a = fmaf(x[r].x, f[j].x, a);
                        a = fmaf(x[r].y, f[j].y, a);
                        a = fmaf(x[r].z, f[j].z, a);
                        a = fmaf(x[r].w, f[j].w, a);
                    }
            }

            // ssq for this wave's two rows: re-read from LDS (no runtime reg index)
            const f32x4 a = *reinterpret_cast<const f32x4*>(&xrow0[idx * 4]);
            const f32x4 b = *reinterpret_cast<const f32x4*>(&xrow1[idx * 4]);
            ssq0 = fmaf(a.x, a.x, ssq0); ssq0 = fmaf(a.y, a.y, ssq0);
            ssq0 = fmaf(a.z, a.z, ssq0); ssq0 = fmaf(a.w, a.w, ssq0);
            ssq1 = fmaf(b.x, b.x, ssq1); ssq1 = fmaf(b.y, b.y, ssq1);
            ssq1 = fmaf(b.z, b.z, ssq1); ssq1 = fmaf(b.w, b.w, ssq1);
        }
    }

    // 64-lane butterfly reduce: 48 dot partials + 2 ssq per wave
    #pragma unroll
    for (int r = 0; r < RPB; ++r)
        #pragma unroll
        for (int j = 0; j < MPW; ++j) {
            float v = acc[r][j];
            #pragma unroll
            for (int off = 32; off >= 1; off >>= 1) v += __shfl_xor(v, off, 64);
            acc[r][j] = v;
        }
    #pragma unroll
    for (int off = 32; off >= 1; off >>= 1) ssq0 += __shfl_xor(ssq0, off, 64);
    #pragma unroll
    for (int off = 32; off >= 1; off >>= 1) ssq1 += __shfl_xor(ssq1, off, 64);

    __syncthreads();
    if (lane == 0) {
        #pragma unroll
        for (int r = 0; r < RPB; ++r)
            #pragma unroll
            for (int j = 0; j < MPW; ++j) s_fin[r * 25 + mg + j] = acc[r][j];
        s_fin[(2 * wave) * 25 + 24]     = ssq0;
        s_fin[(2 * wave + 1) * 25 + 24] = ssq1;
    }
    __syncthreads();

    // epilogue: one thread per row
    if (tid < RPB) {
        const int row = row0 + tid;
        const float* v = &s_fin[tid * 25];
        const float rs = 1.0f / sqrtf(v[24] * (1.0f / (float)DIM) + NORM_EPS);
        const float s0 = scale[0], s1 = scale[1], s2 = scale[2];

        #pragma unroll
        for (int i = 0; i < HC; ++i) {
            const float z = v[i] * rs * s0 + base[i];
            out[PRE_OFF + row * HC + i] = 1.0f / (1.0f + expf(-z)) + HC_EPS;
        }
        #pragma unroll
        for (int i = 0; i < HC; ++i) {
            const float z = v[HC + i] * rs * s1 + base[HC + i];
            out[POST_OFF + row * HC + i] = 2.0f / (1.0f + expf(-z));
        }

        float c[HC][HC];
        #pragma unroll
        for (int i = 0; i < HC; ++i) {
            float l[HC];
            #pragma unroll
            for (int j = 0; j < HC; ++j)
                l[j] = v[2 * HC + i * HC + j] * rs * s2 + base[2 * HC + i * HC + j];
            const float mx = fmaxf(fmaxf(l[0], l[1]), fmaxf(l[2], l[3]));
            float e[HC];
            float sum = 0.0f;
            #pragma unroll
            for (int j = 0; j < HC; ++j) { e[j] = expf(l[j] - mx); sum += e[j]; }
            const float inv = 1.0f / sum;
            #pragma unroll
            for (int j = 0; j < HC; ++j) c[i][j] = e[j] * inv + HC_EPS;
        }
        #pragma unroll
        for (int j = 0; j < HC; ++j) {
            const float cs = c[0][j] + c[1][j] + c[2][j] + c[3][j] + HC_EPS;
            const float inv = 1.0f / cs;
            c[0][j] *= inv; c[1][j] *= inv; c[2][j] *= inv; c[3][j] *= inv;
        }
        #pragma unroll
        for (int it = 0; it < 4; ++it) {
            #pragma unroll
            for (int i = 0; i < HC; ++i) {
                const float rsum = c[i][0] + c[i][1] + c[i][2] + c[i][3] + HC_EPS;
                const float inv = 1.0f / rsum;
                c[i][0] *= inv; c[i][1] *= inv; c[i][2] *= inv; c[i][3] *= inv;
            }
            #pragma unroll
            for (int j = 0; j < HC; ++j) {
                const float cs = c[0][j] + c[1][j] + c[2][j] + c[3][j] + HC_EPS;
                const float inv = 1.0f / cs;
                c[0][j] *= inv; c[1][j] *= inv; c[2][j] *= inv; c[3][j] *= inv;
            }
        }
        #pragma unroll
        for (int i = 0; i < HC; ++i)
            #pragma unroll
            for (int j = 0; j < HC; ++j)
                out[COMB_OFF + row * (HC * HC) + i * HC + j] = c[i][j];
    }
}

extern "C" void kernel_launch(void* const* d_in, const int* in_sizes, int n_in,
                              void* d_out, int out_size, void* d_ws, size_t ws_size,
                              hipStream_t stream) {
    const float* hs    = (const float*)d_in[0];
    const float* fn    = (const float*)d_in[1];
    const float* base  = (const float*)d_in[2];
    const float* scale = (const float*)d_in[3];
    float* out = (float*)d_out;

    const int grid = NROWS / RPB;  // 1024 blocks
    hyperconn_kernel<<<grid, THREADS, 0, stream>>>(hs, fn, base, scale, out);
}